// Round 1
// baseline (3491.538 us; speedup 1.0000x reference)
//
#include <hip/hip_runtime.h>

#define TT 512
#define BB 64
#define EE 256
#define HH 512
#define NWG 64
#define THREADS 256

typedef unsigned short u16;
typedef unsigned int u32;
typedef __attribute__((ext_vector_type(8))) short bh8;
typedef __attribute__((ext_vector_type(4))) float f32x4;

__device__ __forceinline__ u16 f2b(float f) {
  union { float f; u32 u; } v; v.f = f;
  return (u16)((v.u + 0x7fffu + ((v.u >> 16) & 1u)) >> 16);
}
__device__ __forceinline__ float b2f(u16 b) {
  union { u32 u; float f; } v; v.u = ((u32)b) << 16; return v.f;
}
__device__ __forceinline__ float sigm(float x) { return 1.f / (1.f + __expf(-x)); }
__device__ __forceinline__ float tanh_f(float x) {
  float e = __expf(2.f * x);
  return 1.f - 2.f / (e + 1.f);
}

// ---- kernel 0: zero h double-buffer + barrier counter (ws is poisoned 0xAA) ----
__global__ void k_init(u32* __restrict__ hb, u32* __restrict__ c) {
  const int gid = blockIdx.x * 256 + threadIdx.x;
  if (gid < (2 * BB * HH * 2) / 4) hb[gid] = 0u;
  if (gid == 0) *c = 0u;
}

// ---- kernel 1: xe[t][b][e] = bf16(emb[x[t,b]][e]) ----
__global__ __launch_bounds__(256) void k_embed(const int* __restrict__ x,
    const float* __restrict__ emb, u16* __restrict__ xe)
{
  const int gid = blockIdx.x * 256 + threadIdx.x;  // TT*BB*EE/8 threads
  const int tb  = gid >> 5;
  const int e0  = (gid & 31) << 3;
  const int tok = x[tb];
  const float4* s = (const float4*)(emb + (size_t)tok * EE + e0);
  float4 a = s[0], b = s[1];
  u16 o[8] = { f2b(a.x), f2b(a.y), f2b(a.z), f2b(a.w),
               f2b(b.x), f2b(b.y), f2b(b.z), f2b(b.w) };
  *(uint4*)(xe + (size_t)tb * EE + e0) = *(uint4*)o;
}

// ---- kernel 2: persistent gate-partitioned LSTM ----
// WG w owns hidden units [8w, 8w+8) -> 32 gate rows {i,f,g,o} = 2 MFMA N-tiles.
// wave v owns batch rows [16v, 16v+16). h double-buffered in global bf16.
// One agent-scope barrier per step (monotonic counter).
__global__ __launch_bounds__(THREADS, 1) void k_lstm(
    const float* __restrict__ Whh, const float* __restrict__ Wih,
    const float* __restrict__ bih, const float* __restrict__ bhh,
    const u16* __restrict__ xe, const int* __restrict__ xlen,
    u16* __restrict__ hbuf, u32* __restrict__ ctr)
{
  __shared__ u16 lWhh[32 * HH];   // 32 KB, bf16, XOR-swizzled rows
  __shared__ u16 lWih[32 * EE];   // 16 KB

  const int wg   = blockIdx.x;
  const int tid  = threadIdx.x;
  const int wave = tid >> 6;
  const int lane = tid & 63;
  const int n16  = lane & 15;
  const int grp  = lane >> 4;

  // ---- stage weight slices (f32 -> bf16) into LDS, swizzle byte ^= (row&7)<<4 ----
  // local row n in [0,32): global gate row = (n>>3)*HH + wg*8 + (n&7)
  #pragma unroll
  for (int it = 0; it < 8; ++it) {
    int idx = it * THREADS + tid;          // 2048 chunks of 8 cols
    int n   = idx >> 6;
    int c0  = (idx & 63) << 3;
    int grow = (n >> 3) * HH + wg * 8 + (n & 7);
    const float* s = Whh + (size_t)grow * HH + c0;
    u16 tmp[8];
    #pragma unroll
    for (int j = 0; j < 8; ++j) tmp[j] = f2b(s[j]);
    *(uint4*)((char*)lWhh + (u32)(n * 1024 + ((c0 << 1) ^ ((n & 7) << 4)))) = *(uint4*)tmp;
  }
  #pragma unroll
  for (int it = 0; it < 4; ++it) {
    int idx = it * THREADS + tid;          // 1024 chunks of 8 cols
    int n   = idx >> 5;
    int c0  = (idx & 31) << 3;
    int grow = (n >> 3) * HH + wg * 8 + (n & 7);
    const float* s = Wih + (size_t)grow * EE + c0;
    u16 tmp[8];
    #pragma unroll
    for (int j = 0; j < 8; ++j) tmp[j] = f2b(s[j]);
    *(uint4*)((char*)lWih + (u32)(n * 512 + ((c0 << 1) ^ ((n & 7) << 4)))) = *(uint4*)tmp;
  }

  // bias sums for this lane's two gate rows (tile0: i/f, tile1: g/o)
  const int r0 = (n16 < 8) ? (wg * 8 + n16) : (HH + wg * 8 + (n16 - 8));
  const int r1 = (n16 < 8) ? (2 * HH + wg * 8 + n16) : (3 * HH + wg * 8 + (n16 - 8));
  const float bs0 = bih[r0] + bhh[r0];
  const float bs1 = bih[r1] + bhh[r1];

  int   lenr[4];
  int   mrow[4];
  float cst[4] = {0.f, 0.f, 0.f, 0.f};
  float hst[4] = {0.f, 0.f, 0.f, 0.f};
  #pragma unroll
  for (int r = 0; r < 4; ++r) { mrow[r] = wave * 16 + grp * 4 + r; lenr[r] = xlen[mrow[r]]; }
  int wmax = lenr[0];
  #pragma unroll
  for (int r = 1; r < 4; ++r) wmax = max(wmax, lenr[r]);
  #pragma unroll
  for (int off = 1; off < 64; off <<= 1) wmax = max(wmax, __shfl_xor(wmax, off));

  const int  arow = wave * 16 + n16;            // A-fragment batch row
  const u32  swz  = (u32)((n16 & 7) << 4);      // ((16+n16)&7)==(n16&7): same for both tiles
  const char* pWhh0 = (const char*)lWhh + n16 * 1024;
  const char* pWhh1 = (const char*)lWhh + (16 + n16) * 1024;
  const char* pWih0 = (const char*)lWih + n16 * 512;
  const char* pWih1 = (const char*)lWih + (16 + n16) * 512;

  __syncthreads();   // weights staged

  for (int t = 0; t < TT; ++t) {
    const bool active = (t <= wmax);            // wave-uniform

    // xe A-fragments: independent of the barrier -> load before spinning
    bh8 xf[8];
    if (active) {
      const u16* px = xe + ((size_t)t * BB + arow) * EE + grp * 8;
      #pragma unroll
      for (int k = 0; k < 8; ++k) xf[k] = *(const bh8*)(px + k * 32);
    }

    if (t > 0) {
      if (tid == 0) {
        const u32 target = (u32)NWG * (u32)t;
        while (__hip_atomic_load(ctr, __ATOMIC_RELAXED, __HIP_MEMORY_SCOPE_AGENT) < target)
          __builtin_amdgcn_s_sleep(2);
        __threadfence();   // acquire: invalidate L1/L2 so fresh h is fetched
      }
      __syncthreads();
    }

    if (active) {
      // h A-fragments from read buffer (parity t&1)
      const u16* ph = hbuf + (size_t)(t & 1) * (BB * HH) + (size_t)arow * HH + grp * 8;
      bh8 hf[16];
      #pragma unroll
      for (int k = 0; k < 16; ++k) hf[k] = *(const bh8*)(ph + k * 32);

      f32x4 acc0 = {0.f, 0.f, 0.f, 0.f};
      f32x4 acc1 = {0.f, 0.f, 0.f, 0.f};
      // input GEMM (runs while h loads are in flight)
      #pragma unroll
      for (int k = 0; k < 8; ++k) {
        const u32 o = ((u32)(k * 64 + grp * 16)) ^ swz;
        bh8 b0 = *(const bh8*)(pWih0 + o);
        bh8 b1 = *(const bh8*)(pWih1 + o);
        acc0 = __builtin_amdgcn_mfma_f32_16x16x32_bf16(xf[k], b0, acc0, 0, 0, 0);
        acc1 = __builtin_amdgcn_mfma_f32_16x16x32_bf16(xf[k], b1, acc1, 0, 0, 0);
      }
      // recurrent GEMM
      #pragma unroll
      for (int k = 0; k < 16; ++k) {
        const u32 o = ((u32)(k * 64 + grp * 16)) ^ swz;
        bh8 b0 = *(const bh8*)(pWhh0 + o);
        bh8 b1 = *(const bh8*)(pWhh1 + o);
        acc0 = __builtin_amdgcn_mfma_f32_16x16x32_bf16(hf[k], b0, acc0, 0, 0, 0);
        acc1 = __builtin_amdgcn_mfma_f32_16x16x32_bf16(hf[k], b1, acc1, 0, 0, 0);
      }

      // epilogue: C tile row = grp*4+r (batch), col = n16 (gate row)
      u16* hw = hbuf + (size_t)((t & 1) ^ 1) * (BB * HH);
      #pragma unroll
      for (int r = 0; r < 4; ++r) {
        const float v0 = acc0[r] + bs0;          // i (n16<8) / f (n16>=8)
        const float v1 = acc1[r] + bs1;          // g / o
        const float fv = __shfl_xor(v0, 8);
        const float ov = __shfl_xor(v1, 8);
        const float iv = sigm(v0);
        const float ff = sigm(fv);
        const float gv = tanh_f(v1);
        const float oo = sigm(ov);
        const float cn = ff * cst[r] + iv * gv;
        const float hn = oo * tanh_f(cn);
        const bool valid = (t < lenr[r]);        // packed-seq freeze
        cst[r] = valid ? cn : cst[r];
        hst[r] = valid ? hn : hst[r];
        // store through t==len so BOTH parity buffers hold the frozen value
        if (n16 < 8 && t <= lenr[r])
          hw[(size_t)mrow[r] * HH + wg * 8 + n16] = f2b(hst[r]);
      }
    }

    __syncthreads();                              // drains vmcnt (all waves' stores)
    if (tid == 0)
      __hip_atomic_fetch_add(ctr, 1u, __ATOMIC_RELEASE, __HIP_MEMORY_SCOPE_AGENT);
  }
}

// ---- kernel 3: out[b] = sigmoid(h_last[b] . fc_w + fc_b) ----
__global__ __launch_bounds__(64) void k_fc(const u16* __restrict__ h0,
    const float* __restrict__ fcw, const float* __restrict__ fcb,
    float* __restrict__ out)
{
  const int b = blockIdx.x;
  const int lane = threadIdx.x;
  const u16* hr = h0 + (size_t)b * HH;
  float s = 0.f;
  #pragma unroll
  for (int j = 0; j < 8; ++j) {
    const int u = lane + j * 64;
    s += b2f(hr[u]) * fcw[u];
  }
  #pragma unroll
  for (int off = 32; off > 0; off >>= 1) s += __shfl_xor(s, off);
  if (lane == 0) out[b] = sigm(s + fcb[0]);
}

extern "C" void kernel_launch(void* const* d_in, const int* in_sizes, int n_in,
                              void* d_out, int out_size, void* d_ws, size_t ws_size,
                              hipStream_t stream)
{
  const int*   x    = (const int*)  d_in[0];
  const int*   xlen = (const int*)  d_in[1];
  const float* emb  = (const float*)d_in[2];
  const float* Wih  = (const float*)d_in[3];
  const float* Whh  = (const float*)d_in[4];
  const float* bih  = (const float*)d_in[5];
  const float* bhh  = (const float*)d_in[6];
  const float* fcw  = (const float*)d_in[7];
  const float* fcb  = (const float*)d_in[8];
  float* out = (float*)d_out;

  char* ws = (char*)d_ws;
  u16* xe   = (u16*)ws;                                              // 16 MB
  u16* hbuf = (u16*)(ws + (size_t)TT * BB * EE * 2);                 // 128 KB (2 buffers)
  u32* ctr  = (u32*)(ws + (size_t)TT * BB * EE * 2 + (size_t)2 * BB * HH * 2);

  k_init <<<dim3(128), dim3(256), 0, stream>>>((u32*)hbuf, ctr);
  k_embed<<<dim3((TT * BB * EE / 8) / 256), dim3(256), 0, stream>>>(x, emb, xe);
  k_lstm <<<dim3(NWG), dim3(THREADS), 0, stream>>>(Whh, Wih, bih, bhh, xe, xlen, hbuf, ctr);
  k_fc   <<<dim3(BB), dim3(64), 0, stream>>>(hbuf, fcw, fcb, out);
}

// Round 2
// 2234.061 us; speedup vs baseline: 1.5629x; 1.5629x over previous
//
#include <hip/hip_runtime.h>

#define TT 512
#define BB 64
#define EE 256
#define HH 512
#define NWG 64
#define THREADS 256

typedef unsigned short u16;
typedef unsigned int u32;
typedef unsigned long long u64;
typedef __attribute__((ext_vector_type(8))) short bh8;
typedef __attribute__((ext_vector_type(4))) float f32x4;

__device__ __forceinline__ u16 f2b(float f) {
  union { float f; u32 u; } v; v.f = f;
  return (u16)((v.u + 0x7fffu + ((v.u >> 16) & 1u)) >> 16);
}
__device__ __forceinline__ float b2f(u16 b) {
  union { u32 u; float f; } v; v.u = ((u32)b) << 16; return v.f;
}
__device__ __forceinline__ float sigm(float x) { return 1.f / (1.f + __expf(-x)); }
__device__ __forceinline__ float tanh_f(float x) {
  float e = __expf(2.f * x);
  return 1.f - 2.f / (e + 1.f);
}

// ---- kernel 0: zero h double-buffer + per-wave flags (ws is poisoned 0xAA) ----
// hbuf: 2*BB*HH u16 = 131072 B; flags: 256 * 128 B = 32768 B  -> 40960 u32 total
__global__ void k_init(u32* __restrict__ z) {
  const int gid = blockIdx.x * 256 + threadIdx.x;
  if (gid < 40960) z[gid] = 0u;
}

// ---- kernel 1: xe[t][b][e] = bf16(emb[x[t,b]][e]) ----
__global__ __launch_bounds__(256) void k_embed(const int* __restrict__ x,
    const float* __restrict__ emb, u16* __restrict__ xe)
{
  const int gid = blockIdx.x * 256 + threadIdx.x;  // TT*BB*EE/8 threads
  const int tb  = gid >> 5;
  const int e0  = (gid & 31) << 3;
  const int tok = x[tb];
  const float4* s = (const float4*)(emb + (size_t)tok * EE + e0);
  float4 a = s[0], b = s[1];
  u16 o[8] = { f2b(a.x), f2b(a.y), f2b(a.z), f2b(a.w),
               f2b(b.x), f2b(b.y), f2b(b.z), f2b(b.w) };
  *(uint4*)(xe + (size_t)tb * EE + e0) = *(uint4*)o;
}

// ---- kernel 2: persistent gate-partitioned LSTM, fence-free sync ----
// WG w owns hidden units [8w, 8w+8) -> 32 gate rows = 2 MFMA N-tiles.
// Wave v owns batch rows [16v, 16v+16).  The 4 wave-indices are 4 independent
// sync groups of 64 waves (group v only reads/writes rows [16v,16v+16)).
// h exchanged through IF via agent-scope relaxed atomics (sc0 sc1 — bypass the
// non-coherent L1/L2).  No fences, no barriers, no atomic RMW in the loop.
__global__ __launch_bounds__(THREADS, 1) void k_lstm(
    const float* __restrict__ Whh, const float* __restrict__ Wih,
    const float* __restrict__ bih, const float* __restrict__ bhh,
    const u16* __restrict__ xe, const int* __restrict__ xlen,
    u16* __restrict__ hbuf, u32* __restrict__ flags)
{
  __shared__ u16 lWhh[32 * HH];   // 32 KB, bf16, XOR-swizzled rows
  __shared__ u16 lWih[32 * EE];   // 16 KB

  const int wg   = blockIdx.x;
  const int tid  = threadIdx.x;
  const int wave = tid >> 6;
  const int lane = tid & 63;
  const int n16  = lane & 15;
  const int grp  = lane >> 4;

  // ---- stage weight slices (f32 -> bf16) into LDS, swizzle byte ^= (row&7)<<4
  #pragma unroll
  for (int it = 0; it < 8; ++it) {
    int idx = it * THREADS + tid;
    int n   = idx >> 6;
    int c0  = (idx & 63) << 3;
    int grow = (n >> 3) * HH + wg * 8 + (n & 7);
    const float* s = Whh + (size_t)grow * HH + c0;
    u16 tmp[8];
    #pragma unroll
    for (int j = 0; j < 8; ++j) tmp[j] = f2b(s[j]);
    *(uint4*)((char*)lWhh + (u32)(n * 1024 + ((c0 << 1) ^ ((n & 7) << 4)))) = *(uint4*)tmp;
  }
  #pragma unroll
  for (int it = 0; it < 4; ++it) {
    int idx = it * THREADS + tid;
    int n   = idx >> 5;
    int c0  = (idx & 31) << 3;
    int grow = (n >> 3) * HH + wg * 8 + (n & 7);
    const float* s = Wih + (size_t)grow * EE + c0;
    u16 tmp[8];
    #pragma unroll
    for (int j = 0; j < 8; ++j) tmp[j] = f2b(s[j]);
    *(uint4*)((char*)lWih + (u32)(n * 512 + ((c0 << 1) ^ ((n & 7) << 4)))) = *(uint4*)tmp;
  }

  // bias sums for this lane's two gate rows (tile0: i/f, tile1: g/o)
  const int r0 = (n16 < 8) ? (wg * 8 + n16) : (HH + wg * 8 + (n16 - 8));
  const int r1 = (n16 < 8) ? (2 * HH + wg * 8 + n16) : (3 * HH + wg * 8 + (n16 - 8));
  const float bs0 = bih[r0] + bhh[r0];
  const float bs1 = bih[r1] + bhh[r1];

  int   lenr[4];
  int   mrow[4];
  float cst[4] = {0.f, 0.f, 0.f, 0.f};
  float hst[4] = {0.f, 0.f, 0.f, 0.f};
  #pragma unroll
  for (int r = 0; r < 4; ++r) { mrow[r] = wave * 16 + grp * 4 + r; lenr[r] = xlen[mrow[r]]; }
  int wmax = lenr[0];
  #pragma unroll
  for (int r = 1; r < 4; ++r) wmax = max(wmax, lenr[r]);
  #pragma unroll
  for (int off = 1; off < 64; off <<= 1) wmax = max(wmax, __shfl_xor(wmax, off));

  const int  arow = wave * 16 + n16;            // A-fragment batch row
  const u32  swz  = (u32)((n16 & 7) << 4);
  const char* pWhh0 = (const char*)lWhh + n16 * 1024;
  const char* pWhh1 = (const char*)lWhh + (16 + n16) * 1024;
  const char* pWih0 = (const char*)lWih + n16 * 512;
  const char* pWih1 = (const char*)lWih + (16 + n16) * 512;

  u32* myf = flags + (size_t)(wg * 4 + wave) * 32;      // this wave's flag
  u32* pf  = flags + (size_t)(lane * 4 + wave) * 32;    // flag this lane polls

  __syncthreads();   // weights staged (only barrier in the kernel)

  for (int t = 0; t < TT; ++t) {
    if (t > wmax) break;                        // group drained: exit

    // xe A-fragments: independent of sync -> issue before polling
    bh8 xf[8];
    {
      const u16* px = xe + ((size_t)t * BB + arow) * EE + grp * 8;
      #pragma unroll
      for (int k = 0; k < 8; ++k) xf[k] = *(const bh8*)(px + k * 32);
    }

    if (t > 0) {
      u32 v;
      do {
        v = __hip_atomic_load(pf, __ATOMIC_RELAXED, __HIP_MEMORY_SCOPE_AGENT);
      } while (v < (u32)t);
      asm volatile("" ::: "memory");            // compiler barrier: no hoisting
    }

    // h A-fragments: agent-scope loads (sc0 sc1 -> read coherence point)
    const u16* ph = hbuf + (size_t)(t & 1) * (BB * HH) + (size_t)arow * HH + grp * 8;
    bh8 hf[16];
    #pragma unroll
    for (int k = 0; k < 16; ++k) {
      union { u64 u[2]; bh8 v; } c;
      u64* p = (u64*)(ph + k * 32);
      c.u[0] = __hip_atomic_load(p,     __ATOMIC_RELAXED, __HIP_MEMORY_SCOPE_AGENT);
      c.u[1] = __hip_atomic_load(p + 1, __ATOMIC_RELAXED, __HIP_MEMORY_SCOPE_AGENT);
      hf[k] = c.v;
    }

    f32x4 acc0 = {bs0, bs0, bs0, bs0};          // bias pre-folded
    f32x4 acc1 = {bs1, bs1, bs1, bs1};
    // input GEMM (issues while hf loads are in flight)
    #pragma unroll
    for (int k = 0; k < 8; ++k) {
      const u32 o = ((u32)(k * 64 + grp * 16)) ^ swz;
      bh8 b0 = *(const bh8*)(pWih0 + o);
      bh8 b1 = *(const bh8*)(pWih1 + o);
      acc0 = __builtin_amdgcn_mfma_f32_16x16x32_bf16(xf[k], b0, acc0, 0, 0, 0);
      acc1 = __builtin_amdgcn_mfma_f32_16x16x32_bf16(xf[k], b1, acc1, 0, 0, 0);
    }
    // recurrent GEMM
    #pragma unroll
    for (int k = 0; k < 16; ++k) {
      const u32 o = ((u32)(k * 64 + grp * 16)) ^ swz;
      bh8 b0 = *(const bh8*)(pWhh0 + o);
      bh8 b1 = *(const bh8*)(pWhh1 + o);
      acc0 = __builtin_amdgcn_mfma_f32_16x16x32_bf16(hf[k], b0, acc0, 0, 0, 0);
      acc1 = __builtin_amdgcn_mfma_f32_16x16x32_bf16(hf[k], b1, acc1, 0, 0, 0);
    }

    // epilogue: C row = grp*4+r (batch), col = n16 (gate unit)
    u16* hw = hbuf + (size_t)((t & 1) ^ 1) * (BB * HH);
    #pragma unroll
    for (int r = 0; r < 4; ++r) {
      const float v0 = acc0[r];                 // i (n16<8) / f (n16>=8)
      const float v1 = acc1[r];                 // g / o
      const float fv = __shfl_xor(v0, 8);
      const float ov = __shfl_xor(v1, 8);
      const float iv = sigm(v0);
      const float ff = sigm(fv);
      const float gv = tanh_f(v1);
      const float oo = sigm(ov);
      const float cn = ff * cst[r] + iv * gv;
      const float hn = oo * tanh_f(cn);
      const bool valid = (t < lenr[r]);         // packed-seq freeze
      cst[r] = valid ? cn : cst[r];
      hst[r] = valid ? hn : hst[r];
      // pack 2 adjacent units into one u32, write-through (sc0 sc1).
      // store through t==len so BOTH parity buffers hold the frozen value.
      u32 hv = (u32)f2b(hst[r]);
      u32 up = __shfl_xor(hv, 1);
      if (((n16 & 1) == 0) && (n16 < 8) && (t <= lenr[r]))
        __hip_atomic_store((u32*)(hw + (size_t)mrow[r] * HH + wg * 8 + n16),
                           hv | (up << 16), __ATOMIC_RELAXED, __HIP_MEMORY_SCOPE_AGENT);
    }

    // release: write-through stores retired at coherence point -> set flag
    asm volatile("s_waitcnt vmcnt(0)" ::: "memory");
    if (lane == 0)
      __hip_atomic_store(myf, (u32)(t + 1), __ATOMIC_RELAXED, __HIP_MEMORY_SCOPE_AGENT);
  }

  // drained: park flag past the horizon so nobody ever waits on this wave
  asm volatile("s_waitcnt vmcnt(0)" ::: "memory");
  if (lane == 0)
    __hip_atomic_store(myf, (u32)(TT + 1), __ATOMIC_RELAXED, __HIP_MEMORY_SCOPE_AGENT);
}

// ---- kernel 3: out[b] = sigmoid(h_last[b] . fc_w + fc_b) ----
__global__ __launch_bounds__(64) void k_fc(const u16* __restrict__ h0,
    const float* __restrict__ fcw, const float* __restrict__ fcb,
    float* __restrict__ out)
{
  const int b = blockIdx.x;
  const int lane = threadIdx.x;
  const u16* hr = h0 + (size_t)b * HH;
  float s = 0.f;
  #pragma unroll
  for (int j = 0; j < 8; ++j) {
    const int u = lane + j * 64;
    s += b2f(hr[u]) * fcw[u];
  }
  #pragma unroll
  for (int off = 32; off > 0; off >>= 1) s += __shfl_xor(s, off);
  if (lane == 0) out[b] = sigm(s + fcb[0]);
}

extern "C" void kernel_launch(void* const* d_in, const int* in_sizes, int n_in,
                              void* d_out, int out_size, void* d_ws, size_t ws_size,
                              hipStream_t stream)
{
  const int*   x    = (const int*)  d_in[0];
  const int*   xlen = (const int*)  d_in[1];
  const float* emb  = (const float*)d_in[2];
  const float* Wih  = (const float*)d_in[3];
  const float* Whh  = (const float*)d_in[4];
  const float* bih  = (const float*)d_in[5];
  const float* bhh  = (const float*)d_in[6];
  const float* fcw  = (const float*)d_in[7];
  const float* fcb  = (const float*)d_in[8];
  float* out = (float*)d_out;

  char* ws = (char*)d_ws;
  u16* xe    = (u16*)ws;                                             // 16 MB
  u16* hbuf  = (u16*)(ws + (size_t)TT * BB * EE * 2);                // 128 KB
  u32* flags = (u32*)(ws + (size_t)TT * BB * EE * 2 + (size_t)2 * BB * HH * 2); // 32 KB

  k_init <<<dim3(160), dim3(256), 0, stream>>>((u32*)hbuf);
  k_embed<<<dim3((TT * BB * EE / 8) / 256), dim3(256), 0, stream>>>(x, emb, xe);
  k_lstm <<<dim3(NWG), dim3(THREADS), 0, stream>>>(Whh, Wih, bih, bhh, xe, xlen, hbuf, flags);
  k_fc   <<<dim3(BB), dim3(64), 0, stream>>>(hbuf, fcw, fcb, out);
}